// Round 14
// baseline (549.549 us; speedup 1.0000x reference)
//
#include <hip/hip_runtime.h>

// QRNN fo-pool: B=8, C=256, H=256, T=4096, K=2
// PX: x -> xq single-tap frag-packed bf16 (zero pad frag-row at t=-1)      [r13]
// PW: W -> aq frag-packed [hs8][gate][hlf2]                                 [r13]
// G : fully fused: MFMA GEMM 96m x 128t (r13 core) + bias/act + chunk scan
//     + DETERMINISTIC decoupled lookback (atomicAdd tile id, aggregates-only
//     fixed-order walk) + final h,c output. No S2/S3 kernels.
// Flags/counter zeroed via hipMemsetAsync each launch (graph-capturable).

typedef unsigned short ushort_t;
typedef __attribute__((ext_vector_type(8))) short short8_t;
typedef __attribute__((ext_vector_type(4))) float f32x4;

#define B_ 8
#define C_ 256
#define H_ 256
#define T_ 4096
#define NCH 128
#define NTF 257        // frag-rows per b: 1 zero row + 256
#define LS2 130        // scan row stride in bf16 (65 words, odd -> conflict-free)
#define NTILE 32       // t-tiles per carry chain
#define NCHAIN 64      // (b, hs8) chains

__device__ __forceinline__ unsigned short f2bf(float f) {
  unsigned int u = __float_as_uint(f);
  u += 0x7fffu + ((u >> 16) & 1u);
  return (unsigned short)(u >> 16);
}
__device__ __forceinline__ float bf2f(unsigned short u) {
  return __uint_as_float(((unsigned int)u) << 16);
}
__device__ __forceinline__ float sigm(float v) { return 1.f / (1.f + __expf(-v)); }
__device__ __forceinline__ float tanh_f(float v) { return 2.f / (1.f + __expf(-2.f * v)) - 1.f; }

__device__ __forceinline__ void gl16(const ushort_t* g, ushort_t* l) {
  __builtin_amdgcn_global_load_lds(
      (const __attribute__((address_space(1))) unsigned int*)g,
      (__attribute__((address_space(3))) unsigned int*)l, 16, 0, 0);
}

// ---------------- PX: x [B][C][T] f32 -> xq single-tap frag-packed bf16 ------------------
__global__ __launch_bounds__(256) void qrnn_pack_x(const float* __restrict__ x,
                                                   ushort_t* __restrict__ xq) {
  __shared__ float tile[32][129];
  const int tid = threadIdx.x;
  const int t0 = blockIdx.x * 128, c0 = blockIdx.y * 32, b = blockIdx.z;
#pragma unroll
  for (int p = 0; p < 4; ++p) {
    const int j = tid + p * 256;
    const int row = j >> 5, q = j & 31;
    float4 v = *reinterpret_cast<const float4*>(x + ((size_t)(b * C_ + c0 + row)) * T_ + t0 + q * 4);
    tile[row][q * 4 + 0] = v.x; tile[row][q * 4 + 1] = v.y;
    tile[row][q * 4 + 2] = v.z; tile[row][q * 4 + 3] = v.w;
  }
  const int ks0 = c0 >> 5;
  if (blockIdx.x == 0 && tid < 64) {    // zero pad frag-row (t = -16..-1)
    uint4 zz = make_uint4(0, 0, 0, 0);
    *reinterpret_cast<uint4*>(xq + ((size_t)(b * NTF) * 8 + ks0) * 512 + tid * 8) = zz;
  }
  __syncthreads();
#pragma unroll
  for (int q2 = 0; q2 < 2; ++q2) {
    const int p = tid + q2 * 256;
    const int tfl = p >> 6, lane = p & 63;
    const int l15 = lane & 15, g8 = (lane >> 4) * 8;
    const int tcol = tfl * 16 + l15;
    ushort_t o0[8];
#pragma unroll
    for (int j = 0; j < 8; ++j) o0[j] = f2bf(tile[g8 + j][tcol]);
    ushort_t* d0 = xq + ((size_t)(b * NTF + 1 + (t0 >> 4) + tfl) * 8 + ks0) * 512 + lane * 8;
    *reinterpret_cast<uint4*>(d0) = *reinterpret_cast<uint4*>(&o0[0]);
  }
}

// ---------------- PW: W -> aq frag-packed, mf = hs8*6 + g*2 + hlf2 -----------------------
__global__ __launch_bounds__(256) void qrnn_pack_w(const float* __restrict__ Wz,
                                                   const float* __restrict__ Wf,
                                                   const float* __restrict__ Wo,
                                                   ushort_t* __restrict__ aq) {
  const int idx = blockIdx.x * 256 + threadIdx.x;   // < 48*16*64
  const int lane = idx & 63;
  const int ks = (idx >> 6) & 15;
  const int mf = idx >> 10;            // 0..47
  const int hs8 = mf / 6, rem = mf % 6;
  const int g = rem >> 1, hlf2 = rem & 1;
  const int h = hs8 * 32 + hlf2 * 16 + (lane & 15);
  const float* W = (g == 0) ? Wz : ((g == 1) ? Wf : Wo);
  ushort_t o[8];
#pragma unroll
  for (int j = 0; j < 8; ++j) {
    const int k = ks * 32 + (lane >> 4) * 8 + j;
    const int c = k & 255;
    const int tap = (k < 256) ? 1 : 0;
    o[j] = f2bf(W[((size_t)h * C_ + c) * 2 + tap]);
  }
  *reinterpret_cast<uint4*>(aq + (size_t)idx * 8) = *reinterpret_cast<uint4*>(&o[0]);
}

// ---------------- G: fused GEMM + scan + lookback + output -------------------------------
__global__ __launch_bounds__(256, 4) void qrnn_g(const ushort_t* __restrict__ aq,
                                                 const ushort_t* __restrict__ xq,
                                                 const float* __restrict__ bz,
                                                 const float* __restrict__ bfv,
                                                 const float* __restrict__ bo,
                                                 float* __restrict__ outh,
                                                 float* __restrict__ outc,
                                                 float* __restrict__ pubP,
                                                 float* __restrict__ pubC,
                                                 int* __restrict__ flags,
                                                 int* __restrict__ counter) {
  __shared__ __align__(16) char ldsu[28672];
  ushort_t* As = (ushort_t*)ldsu;                   // staging: 12 rows, 12288B
  ushort_t* Bs = (ushort_t*)(ldsu + 12288);         // staging: 16 rows, 16384B
  ushort_t* lzs = (ushort_t*)ldsu;                  // [32][LS2] bf16: z -> c (8320B)
  ushort_t* lfs = (ushort_t*)(ldsu + 8320);         // [32][LS2] bf16: f-0.5
  float* aggLP = (float*)(ldsu + 16640);            // [4][32]
  float* aggLC = (float*)(ldsu + 17152);            // [4][32]
  float* carrySh = (float*)(ldsu + 17664);          // [32]
  int* vtSh = (int*)(ldsu + 17792);

  const int tid = threadIdx.x;
  if (tid == 0) vtSh[0] = atomicAdd(counter, 1);
  __syncthreads();
  const int vt = vtSh[0];                           // tt-minor order: predecessors have lower vt
  const int tt = vt >> 6;                           // 0..31
  const int chain = vt & 63;                        // (b, hs8)
  const int b = chain & 7;
  const int hs8 = chain >> 3;

  const int lane = tid & 63;
  const int wid = tid >> 6;
  const int wm = wid >> 1;                          // 0..1
  const int wt = wid & 1;                           // 0..1
  const int l15 = lane & 15, g4 = lane >> 4;

  const int sh0 = (l15 == 0) ? 1 : 0;
  const int lane0 = lane + (sh0 ? 15 : -1);

  f32x4 acc[3][4];
#pragma unroll
  for (int i = 0; i < 3; ++i)
#pragma unroll
    for (int n = 0; n < 4; ++n) acc[i][n] = (f32x4){0.f, 0.f, 0.f, 0.f};

  __syncthreads();   // vtSh consumed; staging may now overwrite LDS
  for (int kk = 0; kk < 8; ++kk) {
#pragma unroll
    for (int q = 0; q < 3; ++q) {
      const int c = tid + q * 256;                  // [0,768)
      const int row = c >> 6;
      const int mfl = row >> 1, ksl = row & 1;
      gl16(aq + (((size_t)(hs8 * 6 + mfl) * 16 + kk * 2 + ksl) << 9) + lane * 8,
           As + (size_t)(c - lane) * 8);
    }
#pragma unroll
    for (int q = 0; q < 4; ++q) {
      const int c2 = tid + q * 256;                 // [0,1024)
      const int row = c2 >> 6;
      const int tfl = row >> 1, ksl = row & 1;
      const int kg = kk * 2 + ksl;
      const ushort_t* src;
      if (kg < 8)
        src = xq + (((size_t)(b * NTF + 1 + tt * 8 + tfl) * 8 + kg) << 9) + lane * 8;
      else
        src = xq + (((size_t)(b * NTF + 1 + tt * 8 + tfl - sh0) * 8 + (kg - 8)) << 9) + lane0 * 8;
      gl16(src, Bs + (size_t)(c2 - lane) * 8);
    }
    __syncthreads();
#pragma unroll
    for (int l = 0; l < 2; ++l) {
      short8_t bb[4];
#pragma unroll
      for (int n = 0; n < 4; ++n) {
        const int row = (wt * 4 + n) * 2 + l;
        bb[n] = *reinterpret_cast<const short8_t*>(&Bs[(size_t)(row * 64 + lane) * 8]);
      }
#pragma unroll
      for (int i = 0; i < 3; ++i) {
        const int row = (wm * 3 + i) * 2 + l;
        short8_t a = *reinterpret_cast<const short8_t*>(&As[(size_t)(row * 64 + lane) * 8]);
#pragma unroll
        for (int n = 0; n < 4; ++n)
          acc[i][n] = __builtin_amdgcn_mfma_f32_16x16x32_bf16(a, bb[n], acc[i][n], 0, 0, 0);
      }
    }
    __syncthreads();
  }

  // ---- B1: bias+act; z -> lzs, (f-0.5) -> lfs, o stays in regs (wm==1) ----
#pragma unroll
  for (int i = 0; i < 3; ++i) {
    const int mfl = wm * 3 + i;          // 0..5
    const int g = mfl >> 1;              // 0=z 1=f 2=o
    const int hlf2 = mfl & 1;
    const float* bias = (g == 0) ? bz : ((g == 1) ? bfv : bo);
#pragma unroll
    for (int r = 0; r < 4; ++r) {
      const int hl = hlf2 * 16 + g4 * 4 + r;
      const float bvv = bias[hs8 * 32 + hl];
#pragma unroll
      for (int n = 0; n < 4; ++n) {
        const int tl = wt * 64 + n * 16 + l15;
        const float v = acc[i][n][r] + bvv;
        if (g == 0)      lzs[hl * LS2 + tl] = f2bf(tanh_f(v));
        else if (g == 1) lfs[hl * LS2 + tl] = f2bf(sigm(v) - 0.5f);
        else             acc[i][n][r] = sigm(v);   // o kept in registers
      }
    }
  }
  __syncthreads();

  // ---- B2: chunk=32 scan (aggregates only) ----
  if (tid < 128) {
    const int h = tid & 31, ch = tid >> 5;
    const int base = h * LS2 + ch * 32;
    float c = 0.f, p = 1.f;
#pragma unroll
    for (int u = 0; u < 16; ++u) {
      const unsigned vz = *reinterpret_cast<const unsigned*>(&lzs[base + 2 * u]);
      const unsigned vf = *reinterpret_cast<const unsigned*>(&lfs[base + 2 * u]);
      const float f0 = bf2f((ushort_t)(vf & 0xffff)) + 0.5f;
      const float z0 = bf2f((ushort_t)(vz & 0xffff));
      c = f0 * (c - z0) + z0; p *= f0;
      const float f1 = bf2f((ushort_t)(vf >> 16)) + 0.5f;
      const float z1 = bf2f((ushort_t)(vz >> 16));
      c = f1 * (c - z1) + z1; p *= f1;
    }
    aggLP[ch * 32 + h] = p;
    aggLC[ch * 32 + h] = c;
  }
  __syncthreads();

  // ---- publish tile aggregate ----
  if (tid < 32) {
    float Pt = aggLP[tid], Ct = aggLC[tid];
#pragma unroll
    for (int j = 1; j < 4; ++j) {
      const float Pn = aggLP[j * 32 + tid], Cn = aggLC[j * 32 + tid];
      Ct = Cn + Pn * Ct;
      Pt *= Pn;
    }
    const int pidx = (chain * NTILE + tt) * 32 + tid;
    __hip_atomic_store(&pubP[pidx], Pt, __ATOMIC_RELAXED, __HIP_MEMORY_SCOPE_AGENT);
    __hip_atomic_store(&pubC[pidx], Ct, __ATOMIC_RELAXED, __HIP_MEMORY_SCOPE_AGENT);
  }
  __threadfence();
  __syncthreads();
  if (tid == 0)
    __hip_atomic_store(&flags[chain * NTILE + tt], 1, __ATOMIC_RELEASE,
                       __HIP_MEMORY_SCOPE_AGENT);

  // ---- deterministic lookback: fixed-order walk over aggregates ----
  if (tid < 32) {
    float RP = 1.f, RC = 0.f;
    for (int j = tt - 1; j >= 0; --j) {
      const int fidx = chain * NTILE + j;
      if (tid == 0) {
        while (__hip_atomic_load(&flags[fidx], __ATOMIC_ACQUIRE,
                                 __HIP_MEMORY_SCOPE_AGENT) == 0)
          __builtin_amdgcn_s_sleep(2);
      }
      const float Pj = __hip_atomic_load(&pubP[fidx * 32 + tid], __ATOMIC_RELAXED,
                                         __HIP_MEMORY_SCOPE_AGENT);
      const float Cj = __hip_atomic_load(&pubC[fidx * 32 + tid], __ATOMIC_RELAXED,
                                         __HIP_MEMORY_SCOPE_AGENT);
      RC = RC + RP * Cj;
      RP = RP * Pj;
    }
    carrySh[tid] = RC;
  }
  __syncthreads();

  // ---- C: exact re-scan with true carry; c (bf16) into lzs in place ----
  if (tid < 128) {
    const int h = tid & 31, ch = tid >> 5;
    float c = carrySh[h];
#pragma unroll
    for (int j = 0; j < 3; ++j)
      if (j < ch) c = aggLC[j * 32 + h] + aggLP[j * 32 + h] * c;
    const int base = h * LS2 + ch * 32;
#pragma unroll
    for (int u = 0; u < 16; ++u) {
      const unsigned vz = *reinterpret_cast<const unsigned*>(&lzs[base + 2 * u]);
      const unsigned vf = *reinterpret_cast<const unsigned*>(&lfs[base + 2 * u]);
      const float f0 = bf2f((ushort_t)(vf & 0xffff)) + 0.5f;
      const float z0 = bf2f((ushort_t)(vz & 0xffff));
      c = f0 * (c - z0) + z0;
      const unsigned c0w = f2bf(c);
      const float f1 = bf2f((ushort_t)(vf >> 16)) + 0.5f;
      const float z1 = bf2f((ushort_t)(vz >> 16));
      c = f1 * (c - z1) + z1;
      *reinterpret_cast<unsigned*>(&lzs[base + 2 * u]) = c0w | ((unsigned)f2bf(c) << 16);
    }
  }
  __syncthreads();

  // ---- output: waves 0,1 write c (from LDS, coalesced); waves 2,3 write h = o*c ----
  const size_t gb = ((size_t)b * H_ + hs8 * 32) * T_ + tt * 128;
  if (tid < 128) {
#pragma unroll
    for (int q = 0; q < 8; ++q) {
      const int j = tid + q * 128;       // 1024 float4 units over [32][128]
      const int row = j >> 5, c4 = (j & 31) * 4;
      const unsigned v0 = *reinterpret_cast<const unsigned*>(&lzs[row * LS2 + c4]);
      const unsigned v1 = *reinterpret_cast<const unsigned*>(&lzs[row * LS2 + c4 + 2]);
      float4 cv = make_float4(bf2f((ushort_t)(v0 & 0xffff)), bf2f((ushort_t)(v0 >> 16)),
                              bf2f((ushort_t)(v1 & 0xffff)), bf2f((ushort_t)(v1 >> 16)));
      *reinterpret_cast<float4*>(outc + gb + (size_t)row * T_ + c4) = cv;
    }
  } else {
#pragma unroll
    for (int i = 1; i < 3; ++i) {        // wm==1: mfl 4,5 hold o
      const int hlf2 = (3 + i) & 1;      // wm*3+i = 3+i
#pragma unroll
      for (int r = 0; r < 4; ++r) {
        const int hl = hlf2 * 16 + g4 * 4 + r;
#pragma unroll
        for (int n = 0; n < 4; ++n) {
          const int tl = wt * 64 + n * 16 + l15;
          const float cv = bf2f(lzs[hl * LS2 + tl]);
          outh[gb + (size_t)hl * T_ + tl] = acc[i][n][r] * cv;
        }
      }
    }
  }
}

extern "C" void kernel_launch(void* const* d_in, const int* in_sizes, int n_in,
                              void* d_out, int out_size, void* d_ws, size_t ws_size,
                              hipStream_t stream) {
  const float* x  = (const float*)d_in[0];
  const float* Wz = (const float*)d_in[1];
  const float* bz = (const float*)d_in[2];
  const float* Wf = (const float*)d_in[3];
  const float* bfv= (const float*)d_in[4];
  const float* Wo = (const float*)d_in[5];
  const float* bo = (const float*)d_in[6];

  float* outh = (float*)d_out;                        // [B][H][T]
  float* outc = outh + (size_t)B_ * H_ * T_;          // [B][H][T]

  constexpr size_t XQ_OFF  = 0;                       // 16,842,752
  constexpr size_t AQ_OFF  = 16842752;                //    786,432
  constexpr size_t PP_OFF  = 17629184;                //    262,144 (pubP)
  constexpr size_t PC_OFF  = 17891328;                //    262,144 (pubC)
  constexpr size_t FL_OFF  = 18153472;                //      8,192 (flags) + 16 (counter)
  constexpr size_t WS_NEED = 18161680;
  if (ws_size < WS_NEED) return;

  ushort_t* xq  = (ushort_t*)((char*)d_ws + XQ_OFF);
  ushort_t* aq  = (ushort_t*)((char*)d_ws + AQ_OFF);
  float* pubP   = (float*)((char*)d_ws + PP_OFF);
  float* pubC   = (float*)((char*)d_ws + PC_OFF);
  int* flags    = (int*)((char*)d_ws + FL_OFF);
  int* counter  = (int*)((char*)d_ws + FL_OFF + 8192);

  hipMemsetAsync((char*)d_ws + FL_OFF, 0, 8192 + 16, stream);
  qrnn_pack_x<<<dim3(T_ / 128, C_ / 32, B_), 256, 0, stream>>>(x, xq);
  qrnn_pack_w<<<dim3(192), 256, 0, stream>>>(Wz, Wf, Wo, aq);
  qrnn_g<<<dim3(2048), 256, 0, stream>>>(aq, xq, bz, bfv, bo, outh, outc,
                                         pubP, pubC, flags, counter);
}

// Round 15
// 94.795 us; speedup vs baseline: 5.7972x; 5.7972x over previous
//
#include <hip/hip_runtime.h>

// QRNN fo-pool: B=8, C=256, H=256, T=4096, K=2
// PX: x -> xq single-tap frag-packed bf16 (zero pad frag-row at t=-1)
// PW: W -> aq frag-packed [hs8][gate][hlf2]
// G : MFMA GEMM 96m x 128t, 4 waves, BK=64, gl16 staging with STRENGTH-REDUCED
//     pointers (7 src ptrs precomputed, += 1024/step; tap switch via bdelta),
//     fused bf16 scan epilogue. launch_bounds(256,3) (empirical budget 256/arg).
// S2: aggregate scan -> carry_in
// S3: elementwise c = cl + P*carry; h = o*c

typedef unsigned short ushort_t;
typedef __attribute__((ext_vector_type(8))) short short8_t;
typedef __attribute__((ext_vector_type(4))) float f32x4;

#define B_ 8
#define C_ 256
#define H_ 256
#define T_ 4096
#define NCH 128
#define NTF 257        // frag-rows per b: 1 zero row + 256
#define LS2 130        // scan row stride in bf16 (65 words, odd -> conflict-free)

__device__ __forceinline__ unsigned short f2bf(float f) {
  unsigned int u = __float_as_uint(f);
  u += 0x7fffu + ((u >> 16) & 1u);
  return (unsigned short)(u >> 16);
}
__device__ __forceinline__ float bf2f(unsigned short u) {
  return __uint_as_float(((unsigned int)u) << 16);
}
__device__ __forceinline__ float sigm(float v) { return 1.f / (1.f + __expf(-v)); }
__device__ __forceinline__ float tanh_f(float v) { return 2.f / (1.f + __expf(-2.f * v)) - 1.f; }

__device__ __forceinline__ void gl16(const ushort_t* g, ushort_t* l) {
  __builtin_amdgcn_global_load_lds(
      (const __attribute__((address_space(1))) unsigned int*)g,
      (__attribute__((address_space(3))) unsigned int*)l, 16, 0, 0);
}

// ---------------- PX: x [B][C][T] f32 -> xq single-tap frag-packed bf16 ------------------
__global__ __launch_bounds__(256) void qrnn_pack_x(const float* __restrict__ x,
                                                   ushort_t* __restrict__ xq) {
  __shared__ float tile[32][129];
  const int tid = threadIdx.x;
  const int t0 = blockIdx.x * 128, c0 = blockIdx.y * 32, b = blockIdx.z;
#pragma unroll
  for (int p = 0; p < 4; ++p) {
    const int j = tid + p * 256;
    const int row = j >> 5, q = j & 31;
    float4 v = *reinterpret_cast<const float4*>(x + ((size_t)(b * C_ + c0 + row)) * T_ + t0 + q * 4);
    tile[row][q * 4 + 0] = v.x; tile[row][q * 4 + 1] = v.y;
    tile[row][q * 4 + 2] = v.z; tile[row][q * 4 + 3] = v.w;
  }
  const int ks0 = c0 >> 5;
  if (blockIdx.x == 0 && tid < 64) {    // zero pad frag-row (t = -16..-1)
    uint4 zz = make_uint4(0, 0, 0, 0);
    *reinterpret_cast<uint4*>(xq + ((size_t)(b * NTF) * 8 + ks0) * 512 + tid * 8) = zz;
  }
  __syncthreads();
#pragma unroll
  for (int q2 = 0; q2 < 2; ++q2) {
    const int p = tid + q2 * 256;
    const int tfl = p >> 6, lane = p & 63;
    const int l15 = lane & 15, g8 = (lane >> 4) * 8;
    const int tcol = tfl * 16 + l15;
    ushort_t o0[8];
#pragma unroll
    for (int j = 0; j < 8; ++j) o0[j] = f2bf(tile[g8 + j][tcol]);
    ushort_t* d0 = xq + ((size_t)(b * NTF + 1 + (t0 >> 4) + tfl) * 8 + ks0) * 512 + lane * 8;
    *reinterpret_cast<uint4*>(d0) = *reinterpret_cast<uint4*>(&o0[0]);
  }
}

// ---------------- PW: W -> aq frag-packed, mf = hs8*6 + g*2 + hlf2 -----------------------
__global__ __launch_bounds__(256) void qrnn_pack_w(const float* __restrict__ Wz,
                                                   const float* __restrict__ Wf,
                                                   const float* __restrict__ Wo,
                                                   ushort_t* __restrict__ aq) {
  const int idx = blockIdx.x * 256 + threadIdx.x;   // < 48*16*64
  const int lane = idx & 63;
  const int ks = (idx >> 6) & 15;
  const int mf = idx >> 10;            // 0..47
  const int hs8 = mf / 6, rem = mf % 6;
  const int g = rem >> 1, hlf2 = rem & 1;
  const int h = hs8 * 32 + hlf2 * 16 + (lane & 15);
  const float* W = (g == 0) ? Wz : ((g == 1) ? Wf : Wo);
  ushort_t o[8];
#pragma unroll
  for (int j = 0; j < 8; ++j) {
    const int k = ks * 32 + (lane >> 4) * 8 + j;
    const int c = k & 255;
    const int tap = (k < 256) ? 1 : 0;
    o[j] = f2bf(W[((size_t)h * C_ + c) * 2 + tap]);
  }
  *reinterpret_cast<uint4*>(aq + (size_t)idx * 8) = *reinterpret_cast<uint4*>(&o[0]);
}

// ---------------- G: MFMA GEMM 96m x 128t + fused chunk-scan epilogue --------------------
__global__ __launch_bounds__(256, 3) void qrnn_g(const ushort_t* __restrict__ aq,
                                                 const ushort_t* __restrict__ xq,
                                                 const float* __restrict__ bz,
                                                 const float* __restrict__ bfv,
                                                 const float* __restrict__ bo,
                                                 ushort_t* __restrict__ cl,
                                                 ushort_t* __restrict__ pb,
                                                 ushort_t* __restrict__ ob,
                                                 float* __restrict__ aggP,
                                                 float* __restrict__ aggC) {
  __shared__ __align__(16) char ldsu[28672];
  ushort_t* As = (ushort_t*)ldsu;                   // [mfl*2+ksl][lane][8]  12 rows, 12288B
  ushort_t* Bs = (ushort_t*)(ldsu + 12288);         // [tfl*2+ksl][lane][8]  16 rows, 16384B
  ushort_t* lzs = (ushort_t*)ldsu;                  // [32][LS2] bf16: z -> c_local (8320B)
  ushort_t* lfs = (ushort_t*)(ldsu + 8320);         // [32][LS2] bf16: f-0.5 -> P

  const int tid = threadIdx.x;
  const int lane = tid & 63;
  const int wid = tid >> 6;
  const int wm = wid >> 1;                          // 0..1 (m-split 2)
  const int wt = wid & 1;                           // 0..1 (t-split 2)
  const int l15 = lane & 15, g4 = lane >> 4;
  const int bid = blockIdx.x;
  const int b = bid & 7;                            // XCD-local batch
  const int hs8 = (bid >> 3) & 7;                   // 32-h strip
  const int tt = bid >> 6;                          // 0..31, 128 t-cols each

  const int sh0 = (l15 == 0) ? 1 : 0;
  const int lane0 = lane + (sh0 ? 15 : -1);

  // ---- strength-reduced staging pointers (computed once) ----
  const ushort_t* aptr[3];
  int adst[3];
#pragma unroll
  for (int q = 0; q < 3; ++q) {
    const int c = tid + q * 256;                    // [0,768)
    const int row = c >> 6, mfl = row >> 1, ksl = row & 1;
    aptr[q] = aq + (((size_t)(hs8 * 6 + mfl) * 16 + ksl) << 9) + lane * 8;
    adst[q] = (c - lane) * 8;
  }
  const ushort_t* bp[4];
  int bdst[4];
#pragma unroll
  for (int q = 0; q < 4; ++q) {
    const int c2 = tid + q * 256;                   // [0,1024)
    const int row = c2 >> 6, tfl = row >> 1, ksl = row & 1;
    bp[q] = xq + (((size_t)(b * NTF + 1 + tt * 8 + tfl) * 8 + ksl) << 9) + lane * 8;
    bdst[q] = (c2 - lane) * 8;
  }
  // tap0 start = tap1 start - sh0*(8<<9) + (lane0-lane)*8; after 4 steps bp advanced 4096
  const int bdelta = -(sh0 * 4096) + (lane0 - lane) * 8 - 4096;

  f32x4 acc[3][4];
#pragma unroll
  for (int i = 0; i < 3; ++i)
#pragma unroll
    for (int n = 0; n < 4; ++n) acc[i][n] = (f32x4){0.f, 0.f, 0.f, 0.f};

  for (int half = 0; half < 2; ++half) {
    for (int kk2 = 0; kk2 < 4; ++kk2) {
#pragma unroll
      for (int q = 0; q < 3; ++q) { gl16(aptr[q], As + adst[q]); aptr[q] += 1024; }
#pragma unroll
      for (int q = 0; q < 4; ++q) { gl16(bp[q], Bs + bdst[q]); bp[q] += 1024; }
      __syncthreads();
#pragma unroll
      for (int l = 0; l < 2; ++l) {
        short8_t bb[4];
#pragma unroll
        for (int n = 0; n < 4; ++n) {
          const int row = (wt * 4 + n) * 2 + l;
          bb[n] = *reinterpret_cast<const short8_t*>(&Bs[(size_t)(row * 64 + lane) * 8]);
        }
#pragma unroll
        for (int i = 0; i < 3; ++i) {
          const int row = (wm * 3 + i) * 2 + l;
          short8_t a = *reinterpret_cast<const short8_t*>(&As[(size_t)(row * 64 + lane) * 8]);
#pragma unroll
          for (int n = 0; n < 4; ++n)
            acc[i][n] = __builtin_amdgcn_mfma_f32_16x16x32_bf16(a, bb[n], acc[i][n], 0, 0, 0);
        }
      }
      __syncthreads();
    }
    if (half == 0) {
#pragma unroll
      for (int q = 0; q < 4; ++q) bp[q] += bdelta;
    }
  }

  // ---- epilogue B1: bias+act; z -> lzs, (f-0.5) -> lfs, o -> global bf16 ----
#pragma unroll
  for (int i = 0; i < 3; ++i) {
    const int mfl = wm * 3 + i;          // 0..5
    const int g = mfl >> 1;              // 0=z 1=f 2=o
    const int hlf2 = mfl & 1;
    const float* bias = (g == 0) ? bz : ((g == 1) ? bfv : bo);
#pragma unroll
    for (int r = 0; r < 4; ++r) {
      const int hl = hlf2 * 16 + g4 * 4 + r;           // [0,32); C/D: row=(lane>>4)*4+reg
      const float bvv = bias[hs8 * 32 + hl];
#pragma unroll
      for (int n = 0; n < 4; ++n) {
        const int tl = wt * 64 + n * 16 + l15;         // C/D: col=lane&15; [0,128)
        const float v = acc[i][n][r] + bvv;
        if (g == 0)      lzs[hl * LS2 + tl] = f2bf(tanh_f(v));
        else if (g == 1) lfs[hl * LS2 + tl] = f2bf(sigm(v) - 0.5f);
        else ob[((size_t)b * H_ + hs8 * 32 + hl) * T_ + tt * 128 + tl] = f2bf(sigm(v));
      }
    }
  }
  __syncthreads();

  // ---- B2: chunk=32 scan, in place: z->c_local, f->P; aggregates out ----
  if (tid < 128) {
    const int h = tid & 31, ch = tid >> 5;          // 32 h x 4 chunks
    const int base = h * LS2 + ch * 32;
    float c = 0.f, p = 1.f;
#pragma unroll
    for (int u = 0; u < 16; ++u) {
      unsigned vz = *reinterpret_cast<const unsigned*>(&lzs[base + 2 * u]);
      unsigned vf = *reinterpret_cast<const unsigned*>(&lfs[base + 2 * u]);
      const float f0 = bf2f((ushort_t)(vf & 0xffff)) + 0.5f;
      const float z0 = bf2f((ushort_t)(vz & 0xffff));
      c = f0 * (c - z0) + z0; p *= f0;
      const float cl0 = c, pl0 = p;
      const float f1 = bf2f((ushort_t)(vf >> 16)) + 0.5f;
      const float z1 = bf2f((ushort_t)(vz >> 16));
      c = f1 * (c - z1) + z1; p *= f1;
      *reinterpret_cast<unsigned*>(&lzs[base + 2 * u]) =
          (unsigned)f2bf(cl0) | ((unsigned)f2bf(c) << 16);
      *reinterpret_cast<unsigned*>(&lfs[base + 2 * u]) =
          (unsigned)f2bf(pl0) | ((unsigned)f2bf(p) << 16);
    }
    const int chunkg = tt * 4 + ch;
    aggP[((size_t)b * NCH + chunkg) * H_ + hs8 * 32 + h] = p;
    aggC[((size_t)b * NCH + chunkg) * H_ + hs8 * 32 + h] = c;
  }
  __syncthreads();

  // ---- B3: coalesced write-out: c_local bf16, P bf16 ----
  const size_t gb = ((size_t)b * H_ + hs8 * 32) * T_ + tt * 128;
#pragma unroll
  for (int q = 0; q < 2; ++q) {
    const int j = tid + q * 256;         // 512 uint4 units over [32][128] bf16
    const int row = j >> 4, col8 = (j & 15) * 8;
    const int base = row * LS2 + col8;
    uint4 pk;
    pk.x = *reinterpret_cast<const unsigned*>(&lzs[base]);
    pk.y = *reinterpret_cast<const unsigned*>(&lzs[base + 2]);
    pk.z = *reinterpret_cast<const unsigned*>(&lzs[base + 4]);
    pk.w = *reinterpret_cast<const unsigned*>(&lzs[base + 6]);
    *reinterpret_cast<uint4*>(cl + gb + (size_t)row * T_ + col8) = pk;
    pk.x = *reinterpret_cast<const unsigned*>(&lfs[base]);
    pk.y = *reinterpret_cast<const unsigned*>(&lfs[base + 2]);
    pk.z = *reinterpret_cast<const unsigned*>(&lfs[base + 4]);
    pk.w = *reinterpret_cast<const unsigned*>(&lfs[base + 6]);
    *reinterpret_cast<uint4*>(pb + gb + (size_t)row * T_ + col8) = pk;
  }
}

// ---------------- S2: scan over chunk aggregates -> carry_in -----------------------------
__global__ __launch_bounds__(256) void qrnn_s2(const float* __restrict__ aggP,
                                               const float* __restrict__ aggC,
                                               float* __restrict__ cin) {
  const int b = blockIdx.x, h = threadIdx.x;
  float carry = 0.f;
  for (int jb = 0; jb < NCH; jb += 8) {
    float P[8], Cv[8];
#pragma unroll
    for (int u = 0; u < 8; ++u) {
      P[u] = aggP[((size_t)b * NCH + jb + u) * H_ + h];
      Cv[u] = aggC[((size_t)b * NCH + jb + u) * H_ + h];
    }
#pragma unroll
    for (int u = 0; u < 8; ++u) {
      cin[((size_t)b * NCH + jb + u) * H_ + h] = carry;
      carry = Cv[u] + P[u] * carry;
    }
  }
}

// ---------------- S3: elementwise c = cl + P*carry; h = o*c ------------------------------
__global__ __launch_bounds__(256) void qrnn_s3(const ushort_t* __restrict__ cl,
                                               const ushort_t* __restrict__ pb,
                                               const ushort_t* __restrict__ ob,
                                               const float* __restrict__ cin,
                                               float* __restrict__ outc,
                                               float* __restrict__ outh) {
  const int n4 = B_ * H_ * T_ / 4;
  for (int i4 = blockIdx.x * 256 + threadIdx.x; i4 < n4; i4 += gridDim.x * 256) {
    const int idx = i4 << 2;
    const int t = idx & (T_ - 1);
    const int bh = idx >> 12;
    const float carry = cin[((size_t)(bh >> 8) * NCH + (t >> 5)) * H_ + (bh & 255)];
    uint2 cv2 = reinterpret_cast<const uint2*>(cl)[i4];
    uint2 pv = reinterpret_cast<const uint2*>(pb)[i4];
    uint2 ov = reinterpret_cast<const uint2*>(ob)[i4];
    const float c0 = bf2f((ushort_t)(cv2.x & 0xffff)) + bf2f((ushort_t)(pv.x & 0xffff)) * carry;
    const float c1 = bf2f((ushort_t)(cv2.x >> 16)) + bf2f((ushort_t)(pv.x >> 16)) * carry;
    const float c2 = bf2f((ushort_t)(cv2.y & 0xffff)) + bf2f((ushort_t)(pv.y & 0xffff)) * carry;
    const float c3 = bf2f((ushort_t)(cv2.y >> 16)) + bf2f((ushort_t)(pv.y >> 16)) * carry;
    reinterpret_cast<float4*>(outc)[i4] = make_float4(c0, c1, c2, c3);
    reinterpret_cast<float4*>(outh)[i4] =
        make_float4(bf2f((ushort_t)(ov.x & 0xffff)) * c0, bf2f((ushort_t)(ov.x >> 16)) * c1,
                    bf2f((ushort_t)(ov.y & 0xffff)) * c2, bf2f((ushort_t)(ov.y >> 16)) * c3);
  }
}

extern "C" void kernel_launch(void* const* d_in, const int* in_sizes, int n_in,
                              void* d_out, int out_size, void* d_ws, size_t ws_size,
                              hipStream_t stream) {
  const float* x  = (const float*)d_in[0];
  const float* Wz = (const float*)d_in[1];
  const float* bz = (const float*)d_in[2];
  const float* Wf = (const float*)d_in[3];
  const float* bfv= (const float*)d_in[4];
  const float* Wo = (const float*)d_in[5];
  const float* bo = (const float*)d_in[6];

  float* outh = (float*)d_out;                        // [B][H][T]
  float* outc = outh + (size_t)B_ * H_ * T_;          // [B][H][T]

  constexpr size_t XQ_OFF  = 0;                       // 16,842,752
  constexpr size_t AQ_OFF  = 16842752;                //    786,432
  constexpr size_t CL_OFF  = 17629184;                // 16,777,216 (c_local bf16)
  constexpr size_t PB_OFF  = 34406400;                // 16,777,216 (P bf16)
  constexpr size_t OB_OFF  = 51183616;                // 16,777,216 (o bf16)
  constexpr size_t AGP_OFF = 67960832;                //  1,048,576
  constexpr size_t AGC_OFF = 69009408;                //  1,048,576
  constexpr size_t CIN_OFF = 70057984;                //  1,048,576
  constexpr size_t WS_NEED = 71106560;
  if (ws_size < WS_NEED) return;

  ushort_t* xq  = (ushort_t*)((char*)d_ws + XQ_OFF);
  ushort_t* aq  = (ushort_t*)((char*)d_ws + AQ_OFF);
  ushort_t* clb = (ushort_t*)((char*)d_ws + CL_OFF);
  ushort_t* pbb = (ushort_t*)((char*)d_ws + PB_OFF);
  ushort_t* ob  = (ushort_t*)((char*)d_ws + OB_OFF);
  float* aggP   = (float*)((char*)d_ws + AGP_OFF);
  float* aggC   = (float*)((char*)d_ws + AGC_OFF);
  float* cin    = (float*)((char*)d_ws + CIN_OFF);

  qrnn_pack_x<<<dim3(T_ / 128, C_ / 32, B_), 256, 0, stream>>>(x, xq);
  qrnn_pack_w<<<dim3(192), 256, 0, stream>>>(Wz, Wf, Wo, aq);
  qrnn_g<<<dim3(2048), 256, 0, stream>>>(aq, xq, bz, bfv, bo, clb, pbb, ob, aggP, aggC);
  qrnn_s2<<<dim3(B_), 256, 0, stream>>>(aggP, aggC, cin);
  qrnn_s3<<<dim3(2048), 256, 0, stream>>>(clb, pbb, ob, cin, outc, outh);
}

// Round 16
// 88.194 us; speedup vs baseline: 6.2311x; 1.0748x over previous
//
#include <hip/hip_runtime.h>

// QRNN fo-pool: B=8, C=256, H=256, T=4096, K=2  — FINAL (r13 config + PW folded into PX)
// PX: x -> xq single-tap frag-packed bf16 (zero pad frag-row at t=-1); blocks
//     (z==0, x+32y<192) also pack W -> aq frag-packed [hs8][gate][hlf2].
// G : MFMA GEMM 96m x 128t, 4 waves (2m x 2t, wave 48x64), BK=64, gl16 staging,
//     tap-0 via shifted-lane source addresses, 28KB LDS (5 blocks/CU);
//     fused bf16 scan epilogue: z,(f-0.5)->LDS, chunk=32 scan, c_local/P/o bf16 out.
// S2: aggregate scan -> carry_in
// S3: elementwise c = cl + P*carry; h = o*c
// Empirical note: VGPR budget = 256 / launch_bounds_arg2; <=64 regs => full TLP.
// History: 123.8 -> 90.5µs over 15 rounds; gates pinned ~51µs across 8 variants
// (latency plateau of the 2-barrier LDS-staged structure, not a HW roofline).

typedef unsigned short ushort_t;
typedef __attribute__((ext_vector_type(8))) short short8_t;
typedef __attribute__((ext_vector_type(4))) float f32x4;

#define B_ 8
#define C_ 256
#define H_ 256
#define T_ 4096
#define NCH 128
#define NTF 257        // frag-rows per b: 1 zero row + 256
#define LS2 130        // scan row stride in bf16 (65 words, odd -> conflict-free)

__device__ __forceinline__ unsigned short f2bf(float f) {
  unsigned int u = __float_as_uint(f);
  u += 0x7fffu + ((u >> 16) & 1u);
  return (unsigned short)(u >> 16);
}
__device__ __forceinline__ float bf2f(unsigned short u) {
  return __uint_as_float(((unsigned int)u) << 16);
}
__device__ __forceinline__ float sigm(float v) { return 1.f / (1.f + __expf(-v)); }
__device__ __forceinline__ float tanh_f(float v) { return 2.f / (1.f + __expf(-2.f * v)) - 1.f; }

__device__ __forceinline__ void gl16(const ushort_t* g, ushort_t* l) {
  __builtin_amdgcn_global_load_lds(
      (const __attribute__((address_space(1))) unsigned int*)g,
      (__attribute__((address_space(3))) unsigned int*)l, 16, 0, 0);
}

// ---------------- PX: x transpose/pack + (folded) W pack ---------------------------------
// xq[((b*NTF + 1 + tf)*8 + ks)*512 + lane*8 + j] = bf16(x[b][32ks+(lane>>4)*8+j][16tf+(lane&15)])
__global__ __launch_bounds__(256) void qrnn_pack_x(const float* __restrict__ x,
                                                   ushort_t* __restrict__ xq,
                                                   const float* __restrict__ Wz,
                                                   const float* __restrict__ Wf,
                                                   const float* __restrict__ Wo,
                                                   ushort_t* __restrict__ aq) {
  __shared__ float tile[32][129];
  const int tid = threadIdx.x;
  const int t0 = blockIdx.x * 128, c0 = blockIdx.y * 32, b = blockIdx.z;
#pragma unroll
  for (int p = 0; p < 4; ++p) {
    const int j = tid + p * 256;
    const int row = j >> 5, q = j & 31;
    float4 v = *reinterpret_cast<const float4*>(x + ((size_t)(b * C_ + c0 + row)) * T_ + t0 + q * 4);
    tile[row][q * 4 + 0] = v.x; tile[row][q * 4 + 1] = v.y;
    tile[row][q * 4 + 2] = v.z; tile[row][q * 4 + 3] = v.w;
  }
  const int ks0 = c0 >> 5;
  if (blockIdx.x == 0 && tid < 64) {    // zero pad frag-row (t = -16..-1)
    uint4 zz = make_uint4(0, 0, 0, 0);
    *reinterpret_cast<uint4*>(xq + ((size_t)(b * NTF) * 8 + ks0) * 512 + tid * 8) = zz;
  }
  // ---- folded PW: blocks (z==0, x+32y<192) pack one 256-element strip of aq ----
  const int widx = blockIdx.x + 32 * blockIdx.y;     // 0..255
  if (blockIdx.z == 0 && widx < 192) {
    const int idx = widx * 256 + tid;                // < 48*16*64
    const int lane = idx & 63;
    const int ks = (idx >> 6) & 15;
    const int mf = idx >> 10;                        // 0..47
    const int hs8 = mf / 6, rem = mf % 6;
    const int g = rem >> 1, hlf2 = rem & 1;
    const int h = hs8 * 32 + hlf2 * 16 + (lane & 15);
    const float* W = (g == 0) ? Wz : ((g == 1) ? Wf : Wo);
    ushort_t o[8];
#pragma unroll
    for (int j = 0; j < 8; ++j) {
      const int k = ks * 32 + (lane >> 4) * 8 + j;
      const int c = k & 255;
      const int tap = (k < 256) ? 1 : 0;
      o[j] = f2bf(W[((size_t)h * C_ + c) * 2 + tap]);
    }
    *reinterpret_cast<uint4*>(aq + (size_t)idx * 8) = *reinterpret_cast<uint4*>(&o[0]);
  }
  __syncthreads();
#pragma unroll
  for (int q2 = 0; q2 < 2; ++q2) {
    const int p = tid + q2 * 256;
    const int tfl = p >> 6, lane = p & 63;
    const int l15 = lane & 15, g8 = (lane >> 4) * 8;
    const int tcol = tfl * 16 + l15;
    ushort_t o0[8];
#pragma unroll
    for (int j = 0; j < 8; ++j) o0[j] = f2bf(tile[g8 + j][tcol]);
    ushort_t* d0 = xq + ((size_t)(b * NTF + 1 + (t0 >> 4) + tfl) * 8 + ks0) * 512 + lane * 8;
    *reinterpret_cast<uint4*>(d0) = *reinterpret_cast<uint4*>(&o0[0]);
  }
}

// ---------------- G: MFMA GEMM 96m x 128t + fused chunk-scan epilogue --------------------
__global__ __launch_bounds__(256, 4) void qrnn_g(const ushort_t* __restrict__ aq,
                                                 const ushort_t* __restrict__ xq,
                                                 const float* __restrict__ bz,
                                                 const float* __restrict__ bfv,
                                                 const float* __restrict__ bo,
                                                 ushort_t* __restrict__ cl,
                                                 ushort_t* __restrict__ pb,
                                                 ushort_t* __restrict__ ob,
                                                 float* __restrict__ aggP,
                                                 float* __restrict__ aggC) {
  __shared__ __align__(16) char ldsu[28672];
  ushort_t* As = (ushort_t*)ldsu;                   // [mfl*2+ksl][lane][8]  12 rows, 12288B
  ushort_t* Bs = (ushort_t*)(ldsu + 12288);         // [tfl*2+ksl][lane][8]  16 rows, 16384B
  ushort_t* lzs = (ushort_t*)ldsu;                  // [32][LS2] bf16: z -> c_local (8320B)
  ushort_t* lfs = (ushort_t*)(ldsu + 8320);         // [32][LS2] bf16: f-0.5 -> P

  const int tid = threadIdx.x;
  const int lane = tid & 63;
  const int wid = tid >> 6;
  const int wm = wid >> 1;                          // 0..1 (m-split 2)
  const int wt = wid & 1;                           // 0..1 (t-split 2)
  const int l15 = lane & 15, g4 = lane >> 4;
  const int bid = blockIdx.x;
  const int b = bid & 7;                            // XCD-local batch
  const int hs8 = (bid >> 3) & 7;                   // 32-h strip
  const int tt = bid >> 6;                          // 0..31, 128 t-cols each

  const int sh0 = (l15 == 0) ? 1 : 0;
  const int lane0 = lane + (sh0 ? 15 : -1);

  f32x4 acc[3][4];
#pragma unroll
  for (int i = 0; i < 3; ++i)
#pragma unroll
    for (int n = 0; n < 4; ++n) acc[i][n] = (f32x4){0.f, 0.f, 0.f, 0.f};

  for (int kk = 0; kk < 8; ++kk) {
    // ---- stage: 3 A + 4 B gl16 per thread, linear LDS dest ----
#pragma unroll
    for (int q = 0; q < 3; ++q) {
      const int c = tid + q * 256;                  // [0,768)
      const int row = c >> 6;                       // mfl*2+ksl, 12 rows
      const int mfl = row >> 1, ksl = row & 1;
      gl16(aq + (((size_t)(hs8 * 6 + mfl) * 16 + kk * 2 + ksl) << 9) + lane * 8,
           As + (size_t)(c - lane) * 8);
    }
#pragma unroll
    for (int q = 0; q < 4; ++q) {
      const int c2 = tid + q * 256;                 // [0,1024)
      const int row = c2 >> 6;                      // tfl*2+ksl, 16 rows
      const int tfl = row >> 1, ksl = row & 1;
      const int kg = kk * 2 + ksl;
      const ushort_t* src;
      if (kg < 8)
        src = xq + (((size_t)(b * NTF + 1 + tt * 8 + tfl) * 8 + kg) << 9) + lane * 8;
      else
        src = xq + (((size_t)(b * NTF + 1 + tt * 8 + tfl - sh0) * 8 + (kg - 8)) << 9) + lane0 * 8;
      gl16(src, Bs + (size_t)(c2 - lane) * 8);
    }
    __syncthreads();
    // ---- compute: per ksl: preload bb[4], then i-loop {read a, 4 MFMA} ----
#pragma unroll
    for (int l = 0; l < 2; ++l) {
      short8_t bb[4];
#pragma unroll
      for (int n = 0; n < 4; ++n) {
        const int row = (wt * 4 + n) * 2 + l;
        bb[n] = *reinterpret_cast<const short8_t*>(&Bs[(size_t)(row * 64 + lane) * 8]);
      }
#pragma unroll
      for (int i = 0; i < 3; ++i) {
        const int row = (wm * 3 + i) * 2 + l;
        short8_t a = *reinterpret_cast<const short8_t*>(&As[(size_t)(row * 64 + lane) * 8]);
#pragma unroll
        for (int n = 0; n < 4; ++n)
          acc[i][n] = __builtin_amdgcn_mfma_f32_16x16x32_bf16(a, bb[n], acc[i][n], 0, 0, 0);
      }
    }
    __syncthreads();
  }

  // ---- epilogue B1: bias+act; z -> lzs, (f-0.5) -> lfs, o -> global bf16 ----
#pragma unroll
  for (int i = 0; i < 3; ++i) {
    const int mfl = wm * 3 + i;          // 0..5
    const int g = mfl >> 1;              // 0=z 1=f 2=o
    const int hlf2 = mfl & 1;
    const float* bias = (g == 0) ? bz : ((g == 1) ? bfv : bo);
#pragma unroll
    for (int r = 0; r < 4; ++r) {
      const int hl = hlf2 * 16 + g4 * 4 + r;           // [0,32); C/D: row=(lane>>4)*4+reg
      const float bvv = bias[hs8 * 32 + hl];
#pragma unroll
      for (int n = 0; n < 4; ++n) {
        const int tl = wt * 64 + n * 16 + l15;         // C/D: col=lane&15; [0,128)
        const float v = acc[i][n][r] + bvv;
        if (g == 0)      lzs[hl * LS2 + tl] = f2bf(tanh_f(v));
        else if (g == 1) lfs[hl * LS2 + tl] = f2bf(sigm(v) - 0.5f);
        else ob[((size_t)b * H_ + hs8 * 32 + hl) * T_ + tt * 128 + tl] = f2bf(sigm(v));
      }
    }
  }
  __syncthreads();

  // ---- B2: chunk=32 scan, in place: z->c_local, f->P; aggregates out ----
  if (tid < 128) {
    const int h = tid & 31, ch = tid >> 5;          // 32 h x 4 chunks
    const int base = h * LS2 + ch * 32;
    float c = 0.f, p = 1.f;
#pragma unroll
    for (int u = 0; u < 16; ++u) {
      unsigned vz = *reinterpret_cast<const unsigned*>(&lzs[base + 2 * u]);
      unsigned vf = *reinterpret_cast<const unsigned*>(&lfs[base + 2 * u]);
      const float f0 = bf2f((ushort_t)(vf & 0xffff)) + 0.5f;
      const float z0 = bf2f((ushort_t)(vz & 0xffff));
      c = f0 * (c - z0) + z0; p *= f0;
      const float cl0 = c, pl0 = p;
      const float f1 = bf2f((ushort_t)(vf >> 16)) + 0.5f;
      const float z1 = bf2f((ushort_t)(vz >> 16));
      c = f1 * (c - z1) + z1; p *= f1;
      *reinterpret_cast<unsigned*>(&lzs[base + 2 * u]) =
          (unsigned)f2bf(cl0) | ((unsigned)f2bf(c) << 16);
      *reinterpret_cast<unsigned*>(&lfs[base + 2 * u]) =
          (unsigned)f2bf(pl0) | ((unsigned)f2bf(p) << 16);
    }
    const int chunkg = tt * 4 + ch;
    aggP[((size_t)b * NCH + chunkg) * H_ + hs8 * 32 + h] = p;
    aggC[((size_t)b * NCH + chunkg) * H_ + hs8 * 32 + h] = c;
  }
  __syncthreads();

  // ---- B3: coalesced write-out: c_local bf16, P bf16 ----
  const size_t gb = ((size_t)b * H_ + hs8 * 32) * T_ + tt * 128;
#pragma unroll
  for (int q = 0; q < 2; ++q) {
    const int j = tid + q * 256;         // 512 uint4 units over [32][128] bf16
    const int row = j >> 4, col8 = (j & 15) * 8;
    const int base = row * LS2 + col8;
    uint4 pk;
    pk.x = *reinterpret_cast<const unsigned*>(&lzs[base]);
    pk.y = *reinterpret_cast<const unsigned*>(&lzs[base + 2]);
    pk.z = *reinterpret_cast<const unsigned*>(&lzs[base + 4]);
    pk.w = *reinterpret_cast<const unsigned*>(&lzs[base + 6]);
    *reinterpret_cast<uint4*>(cl + gb + (size_t)row * T_ + col8) = pk;
    pk.x = *reinterpret_cast<const unsigned*>(&lfs[base]);
    pk.y = *reinterpret_cast<const unsigned*>(&lfs[base + 2]);
    pk.z = *reinterpret_cast<const unsigned*>(&lfs[base + 4]);
    pk.w = *reinterpret_cast<const unsigned*>(&lfs[base + 6]);
    *reinterpret_cast<uint4*>(pb + gb + (size_t)row * T_ + col8) = pk;
  }
}

// ---------------- S2: scan over chunk aggregates -> carry_in -----------------------------
__global__ __launch_bounds__(256) void qrnn_s2(const float* __restrict__ aggP,
                                               const float* __restrict__ aggC,
                                               float* __restrict__ cin) {
  const int b = blockIdx.x, h = threadIdx.x;
  float carry = 0.f;
  for (int jb = 0; jb < NCH; jb += 8) {
    float P[8], Cv[8];
#pragma unroll
    for (int u = 0; u < 8; ++u) {
      P[u] = aggP[((size_t)b * NCH + jb + u) * H_ + h];
      Cv[u] = aggC[((size_t)b * NCH + jb + u) * H_ + h];
    }
#pragma unroll
    for (int u = 0; u < 8; ++u) {
      cin[((size_t)b * NCH + jb + u) * H_ + h] = carry;
      carry = Cv[u] + P[u] * carry;
    }
  }
}

// ---------------- S3: elementwise c = cl + P*carry; h = o*c ------------------------------
__global__ __launch_bounds__(256) void qrnn_s3(const ushort_t* __restrict__ cl,
                                               const ushort_t* __restrict__ pb,
                                               const ushort_t* __restrict__ ob,
                                               const float* __restrict__ cin,
                                               float* __restrict__ outc,
                                               float* __restrict__ outh) {
  const int n4 = B_ * H_ * T_ / 4;
  for (int i4 = blockIdx.x * 256 + threadIdx.x; i4 < n4; i4 += gridDim.x * 256) {
    const int idx = i4 << 2;
    const int t = idx & (T_ - 1);
    const int bh = idx >> 12;
    const float carry = cin[((size_t)(bh >> 8) * NCH + (t >> 5)) * H_ + (bh & 255)];
    uint2 cv2 = reinterpret_cast<const uint2*>(cl)[i4];
    uint2 pv = reinterpret_cast<const uint2*>(pb)[i4];
    uint2 ov = reinterpret_cast<const uint2*>(ob)[i4];
    const float c0 = bf2f((ushort_t)(cv2.x & 0xffff)) + bf2f((ushort_t)(pv.x & 0xffff)) * carry;
    const float c1 = bf2f((ushort_t)(cv2.x >> 16)) + bf2f((ushort_t)(pv.x >> 16)) * carry;
    const float c2 = bf2f((ushort_t)(cv2.y & 0xffff)) + bf2f((ushort_t)(pv.y & 0xffff)) * carry;
    const float c3 = bf2f((ushort_t)(cv2.y >> 16)) + bf2f((ushort_t)(pv.y >> 16)) * carry;
    reinterpret_cast<float4*>(outc)[i4] = make_float4(c0, c1, c2, c3);
    reinterpret_cast<float4*>(outh)[i4] =
        make_float4(bf2f((ushort_t)(ov.x & 0xffff)) * c0, bf2f((ushort_t)(ov.x >> 16)) * c1,
                    bf2f((ushort_t)(ov.y & 0xffff)) * c2, bf2f((ushort_t)(ov.y >> 16)) * c3);
  }
}

extern "C" void kernel_launch(void* const* d_in, const int* in_sizes, int n_in,
                              void* d_out, int out_size, void* d_ws, size_t ws_size,
                              hipStream_t stream) {
  const float* x  = (const float*)d_in[0];
  const float* Wz = (const float*)d_in[1];
  const float* bz = (const float*)d_in[2];
  const float* Wf = (const float*)d_in[3];
  const float* bfv= (const float*)d_in[4];
  const float* Wo = (const float*)d_in[5];
  const float* bo = (const float*)d_in[6];

  float* outh = (float*)d_out;                        // [B][H][T]
  float* outc = outh + (size_t)B_ * H_ * T_;          // [B][H][T]

  constexpr size_t XQ_OFF  = 0;                       // 16,842,752
  constexpr size_t AQ_OFF  = 16842752;                //    786,432
  constexpr size_t CL_OFF  = 17629184;                // 16,777,216 (c_local bf16)
  constexpr size_t PB_OFF  = 34406400;                // 16,777,216 (P bf16)
  constexpr size_t OB_OFF  = 51183616;                // 16,777,216 (o bf16)
  constexpr size_t AGP_OFF = 67960832;                //  1,048,576
  constexpr size_t AGC_OFF = 69009408;                //  1,048,576
  constexpr size_t CIN_OFF = 70057984;                //  1,048,576
  constexpr size_t WS_NEED = 71106560;
  if (ws_size < WS_NEED) return;

  ushort_t* xq  = (ushort_t*)((char*)d_ws + XQ_OFF);
  ushort_t* aq  = (ushort_t*)((char*)d_ws + AQ_OFF);
  ushort_t* clb = (ushort_t*)((char*)d_ws + CL_OFF);
  ushort_t* pbb = (ushort_t*)((char*)d_ws + PB_OFF);
  ushort_t* ob  = (ushort_t*)((char*)d_ws + OB_OFF);
  float* aggP   = (float*)((char*)d_ws + AGP_OFF);
  float* aggC   = (float*)((char*)d_ws + AGC_OFF);
  float* cin    = (float*)((char*)d_ws + CIN_OFF);

  qrnn_pack_x<<<dim3(T_ / 128, C_ / 32, B_), 256, 0, stream>>>(x, xq, Wz, Wf, Wo, aq);
  qrnn_g<<<dim3(2048), 256, 0, stream>>>(aq, xq, bz, bfv, bo, clb, pbb, ob, aggP, aggC);
  qrnn_s2<<<dim3(B_), 256, 0, stream>>>(aggP, aggC, cin);
  qrnn_s3<<<dim3(2048), 256, 0, stream>>>(clb, pbb, ob, cin, outc, outh);
}